// Round 1
// 2195.497 us; speedup vs baseline: 2.6442x; 2.6442x over previous
//
#include <hip/hip_runtime.h>

#define NB 32
#define NT 512
#define NI 512
#define NH 512
#define NG 2048
#define GH (NG*NH)
#define BTH ((size_t)NB*NT*NH)   // 8388608
#define BH  (NB*NH)              // 16384

typedef unsigned int uint;
typedef unsigned long long u64;
typedef _Float16 v2h __attribute__((ext_vector_type(2)));

// ---- ws layout (bytes) ----
#define OFF_XPROJ 0
#define SZ_XPROJ  ((size_t)NB*NT*NG*2)            // 64 MB  x_proj bf16 [B][T][G]
#define OFF_BIAS  (OFF_XPROJ + SZ_XPROJ)
#define SZ_BIAS   ((size_t)NB*NG*4)               // 256 KB fp32 bias [B][G]
#define OFF_HP    (OFF_BIAS + SZ_BIAS)
#define SZ_HP     ((size_t)2*NB*256*8)            // 128 KB tagged {f16x2,tag} pairs, dbuf

__device__ __forceinline__ float bf2f(unsigned short u) {
    union { uint i; float f; } v; v.i = ((uint)u) << 16; return v.f;
}
__device__ __forceinline__ unsigned short f2bf(float f) {
    union { uint i; float f; } v; v.f = f;
    uint r = v.i + 0x7FFFu + ((v.i >> 16) & 1u);
    return (unsigned short)(r >> 16);
}
__device__ __forceinline__ uint pkf16(float a, float b) {
    auto p = __builtin_amdgcn_cvt_pkrtz(a, b);   // __fp16 ext_vector(2)
    return __builtin_bit_cast(uint, p);
}
__device__ __forceinline__ float dot2(uint wu, uint hu, float c) {
#if __has_builtin(__builtin_amdgcn_fdot2)
    return __builtin_amdgcn_fdot2(__builtin_bit_cast(v2h, wu),
                                  __builtin_bit_cast(v2h, hu), c, false);
#else
    v2h a = __builtin_bit_cast(v2h, wu), b = __builtin_bit_cast(v2h, hu);
    return c + (float)a[0] * (float)b[0] + (float)a[1] * (float)b[1];
#endif
}
// z = clip(1.2*sigmoid(1.5*(log(eps)-log(1-eps)+m)) - 0.1, 0, 1)
__device__ __forceinline__ float gate_z(float eps, float m) {
    float u = (__logf(eps) - __logf(1.0f - eps) + m) * 1.5f;
    float y = 1.0f / (1.0f + __expf(-u));
    float z = fmaf(y, 1.2f, -0.1f);
    return fminf(fmaxf(z, 0.0f), 1.0f);
}
__device__ __forceinline__ float sigmoidf_(float x) {
    return 1.0f / (1.0f + __expf(-x));
}
__device__ __forceinline__ float tanhf_(float x) {
    return 1.0f - 2.0f / (__expf(2.0f * x) + 1.0f);
}
// LDS swizzle for hsh: 2-way max bank aliasing for 16B reads (free per m136)
__device__ __forceinline__ int hswz(int kg, int r, int u) {
    return (kg << 4) + (((r + (kg >> 1)) & 3) << 2) + u;
}

// ---------- bias[b][g] ----------
__global__ __launch_bounds__(256) void k_bias(
    const float* __restrict__ eb1, const float* __restrict__ eb2,
    const float* __restrict__ mb1, const float* __restrict__ mb2,
    const float* __restrict__ b1, const float* __restrict__ b2,
    float* __restrict__ bias) {
    int idx = blockIdx.x * 256 + threadIdx.x;
    int g = idx & (NG - 1);
    bias[idx] = gate_z(eb1[idx], mb1[g]) * b1[g] + gate_z(eb2[idx], mb2[g]) * b2[g];
}

// ---------- x_proj[b][t][g] (gating of Wih fused) ----------
__global__ __launch_bounds__(256) void k_xproj(
    const float* __restrict__ seq, const float* __restrict__ eps_ih,
    const float* __restrict__ mask_ih, const float* __restrict__ w_ih,
    const float* __restrict__ bias, unsigned short* __restrict__ xproj) {
    __shared__ float As[128 * 33];
    __shared__ float Ws[32 * 68];
    int g0 = blockIdx.x * 64;
    int t0 = blockIdx.y * 128;
    int b  = blockIdx.z;
    int tid = threadIdx.x;
    int gq = tid & 15;
    int rq = tid >> 4;
    float acc[4][8];
#pragma unroll
    for (int c = 0; c < 4; ++c)
#pragma unroll
        for (int k = 0; k < 8; ++k) acc[c][k] = 0.0f;

    for (int i0 = 0; i0 < NI; i0 += 32) {
        __syncthreads();
#pragma unroll
        for (int k = 0; k < 4; ++k) {
            int e = (tid + (k << 8)) << 2;
            int r = e >> 5, c = e & 31;
            float4 v = *(const float4*)(seq + (b * NT + t0 + r) * NI + i0 + c);
            As[r * 33 + c    ] = v.x;
            As[r * 33 + c + 1] = v.y;
            As[r * 33 + c + 2] = v.z;
            As[r * 33 + c + 3] = v.w;
        }
#pragma unroll
        for (int k = 0; k < 2; ++k) {
            int e = (tid + (k << 8)) << 2;
            int gr = e >> 5, c = e & 31;
            int mo = (g0 + gr) * NI + i0 + c;
            int eo = b * GH + mo;
            float4 ev = *(const float4*)(eps_ih + eo);
            float4 mv = *(const float4*)(mask_ih + mo);
            float4 wv = *(const float4*)(w_ih + mo);
            Ws[(c    ) * 68 + gr] = gate_z(ev.x, mv.x) * wv.x;
            Ws[(c + 1) * 68 + gr] = gate_z(ev.y, mv.y) * wv.y;
            Ws[(c + 2) * 68 + gr] = gate_z(ev.z, mv.z) * wv.z;
            Ws[(c + 3) * 68 + gr] = gate_z(ev.w, mv.w) * wv.w;
        }
        __syncthreads();
#pragma unroll 4
        for (int i = 0; i < 32; ++i) {
            float4 wv = *(const float4*)&Ws[i * 68 + (gq << 2)];
#pragma unroll
            for (int k = 0; k < 8; ++k) {
                float av = As[(rq + (k << 4)) * 33 + i];
                acc[0][k] = fmaf(wv.x, av, acc[0][k]);
                acc[1][k] = fmaf(wv.y, av, acc[1][k]);
                acc[2][k] = fmaf(wv.z, av, acc[2][k]);
                acc[3][k] = fmaf(wv.w, av, acc[3][k]);
            }
        }
    }
    float bs[4];
#pragma unroll
    for (int c = 0; c < 4; ++c) bs[c] = bias[b * NG + g0 + (gq << 2) + c];
#pragma unroll
    for (int k = 0; k < 8; ++k) {
        int r = t0 + rq + (k << 4);
        unsigned short* op = xproj + (b * NT + r) * NG + g0 + (gq << 2);
        union { uint2 v; unsigned short s[4]; } o;
        o.s[0] = f2bf(acc[0][k] + bs[0]);
        o.s[1] = f2bf(acc[1][k] + bs[1]);
        o.s[2] = f2bf(acc[2][k] + bs[2]);
        o.s[3] = f2bf(acc[3][k] + bs[3]);
        *(uint2*)op = o.v;
    }
}

// ---------- Persistent recurrence: weights resident in VGPRs ----------
// 256 blocks x 1024 threads, 1 block/CU. block bb: batch b=bb>>3, slice (bb&7)*64.
// thread: wave wv, lane l; j = slice*64 + wv*4 + (l>>4); kg = l&15 owns 32 k's.
// h exchange: single tagged 8B relaxed agent-scope atomic per h-pair:
//   low32 = pkf16(h[2p],h[2p+1]), high32 = tag (= t+1 when produced at step t).
// Consumers spin RELAXED on the word itself (no acquire fences, no buffer_inv,
// no separate flag barrier): data rides in the same atomic word as the tag.
__global__ __launch_bounds__(1024, 4) void k_recur(
    const float* __restrict__ eps, const float* __restrict__ mask,
    const float* __restrict__ w, const unsigned short* __restrict__ xproj,
    u64* __restrict__ hpk, float* __restrict__ out) {
    __shared__ uint hsh[2][256];   // double-buffered packed f16 h pairs (swizzled)
    int bb = blockIdx.x;
    int b = bb >> 3, slice = bb & 7;
    int tid = threadIdx.x;
    int wv = tid >> 6, lane = tid & 63;
    int jj = lane >> 4, kg = lane & 15;
    int j = (slice << 6) + (wv << 2) + jj;
    bool leader = (kg == 0);

    // ---- one-time: load + gate + f16-pack weights into registers ----
    uint wreg[4][16];
#pragma unroll
    for (int q = 0; q < 4; ++q) {
        size_t off = (size_t)((q << 9) + j) * NH + (kg << 5);
        const float2* ep = (const float2*)(eps + (size_t)b * GH + off);
        const float2* mp = (const float2*)(mask + off);
        const float2* wp = (const float2*)(w + off);
#pragma unroll
        for (int u = 0; u < 16; ++u) {
            float2 e = ep[u], m = mp[u], ww = wp[u];
            wreg[q][u] = pkf16(gate_z(e.x, m.x) * ww.x,
                               gate_z(e.y, m.y) * ww.y);
        }
    }

    // prefetch xproj for t=0
    float xp0 = 0.f, xp1 = 0.f, xp2 = 0.f, xp3 = 0.f;
    if (leader) {
        const unsigned short* xq = xproj + ((size_t)(b * NT) << 11) + j;
        xp0 = bf2f(xq[0]); xp1 = bf2f(xq[512]);
        xp2 = bf2f(xq[1024]); xp3 = bf2f(xq[1536]);
    }

    float c = 0.0f;
    for (int t = 0; t < NT; ++t) {
        int par = t & 1;
        // stage remote h pairs: spin on tagged words (relaxed; tag exact-match so
        // stale tags from a previous run / step t-2 can never false-trigger).
        // local words (tid>>5 == slice) were written into LDS by our own leaders
        // at step t-1 (t=0: buffer 0 is memset -> tag 0, payload h=0, stage all).
        if (tid < 256 && !(t > 0 && (tid >> 5) == slice)) {
            const u64* src = hpk + ((size_t)(par * NB + b) << 8) + tid;
            u64 v;
            do {
                v = __hip_atomic_load(src, __ATOMIC_RELAXED, __HIP_MEMORY_SCOPE_AGENT);
            } while ((uint)(v >> 32) != (uint)t);
            hsh[par][hswz(tid >> 4, (tid >> 2) & 3, tid & 3)] = (uint)v;
        }
        __syncthreads();   // single barrier per step (LDS is double-buffered)

        float a0 = 0.f, a1 = 0.f, a2 = 0.f, a3 = 0.f;
#pragma unroll
        for (int r = 0; r < 4; ++r) {
            uint4 hv = *(const uint4*)&hsh[par][hswz(kg, r, 0)];
            uint hu[4] = {hv.x, hv.y, hv.z, hv.w};
#pragma unroll
            for (int u = 0; u < 4; ++u) {
                a0 = dot2(wreg[0][(r << 2) + u], hu[u], a0);
                a1 = dot2(wreg[1][(r << 2) + u], hu[u], a1);
                a2 = dot2(wreg[2][(r << 2) + u], hu[u], a2);
                a3 = dot2(wreg[3][(r << 2) + u], hu[u], a3);
            }
        }
#pragma unroll
        for (int off = 8; off > 0; off >>= 1) {
            a0 += __shfl_xor(a0, off);
            a1 += __shfl_xor(a1, off);
            a2 += __shfl_xor(a2, off);
            a3 += __shfl_xor(a3, off);
        }
        if (leader) {
            float gi = a0 + xp0, gf = a1 + xp1, gg = a2 + xp2, go = a3 + xp3;
            c = fmaf(sigmoidf_(gf), c, sigmoidf_(gi) * tanhf_(gg));
            float h = sigmoidf_(go) * tanhf_(c);
            out[((size_t)(b * NT + t) << 9) + j] = h;
            if (t == NT - 1) {
                out[BTH + (size_t)(b << 9) + j] = h;
                out[BTH + BH + (size_t)(b << 9) + j] = c;
            }
            // pack h pair across leader lanes (0<->16, 32<->48; all four active)
            float hpart = __shfl_xor(h, 16);
            if ((lane & 16) == 0) {   // lanes 0 and 32: own pair words
                uint pk = pkf16(h, hpart);           // lo = even j, hi = odd j
                int wd = (slice << 5) + (wv << 1) + (lane >> 5);
                u64 val = ((u64)(uint)(t + 1) << 32) | (u64)pk;
                // publish to the other 7 blocks (one-way, fire and forget)
                __hip_atomic_store(hpk + ((size_t)(((t + 1) & 1) * NB + b) << 8) + wd,
                                   val, __ATOMIC_RELAXED, __HIP_MEMORY_SCOPE_AGENT);
                // local shortcut: write own pair straight into next LDS buffer
                hsh[(t + 1) & 1][hswz(wd >> 4, (wd >> 2) & 3, wd & 3)] = pk;
            }
            // prefetch xproj for t+1 (absorbed by next step's poll phase)
            if (t + 1 < NT) {
                const unsigned short* xq = xproj + ((size_t)(b * NT + t + 1) << 11) + j;
                xp0 = bf2f(xq[0]); xp1 = bf2f(xq[512]);
                xp2 = bf2f(xq[1024]); xp3 = bf2f(xq[1536]);
            }
        }
    }
}

extern "C" void kernel_launch(void* const* d_in, const int* in_sizes, int n_in,
                              void* d_out, int out_size, void* d_ws, size_t ws_size,
                              hipStream_t stream) {
    const float* seq      = (const float*)d_in[0];
    const float* w_ih     = (const float*)d_in[1];
    const float* w_hh     = (const float*)d_in[2];
    const float* b_ih     = (const float*)d_in[3];
    const float* b_hh     = (const float*)d_in[4];
    const float* mask_ih  = (const float*)d_in[5];
    const float* mask_hh  = (const float*)d_in[6];
    const float* mask_bih = (const float*)d_in[7];
    const float* mask_bhh = (const float*)d_in[8];
    const float* eps_ih   = (const float*)d_in[9];
    const float* eps_hh   = (const float*)d_in[10];
    const float* eps_bih  = (const float*)d_in[11];
    const float* eps_bhh  = (const float*)d_in[12];

    char* ws = (char*)d_ws;
    unsigned short* xproj = (unsigned short*)(ws + OFF_XPROJ);
    float* bias  = (float*)(ws + OFF_BIAS);
    u64*   hpk   = (u64*)(ws + OFF_HP);
    float* out   = (float*)d_out;

    // zero buffer 0 of the tagged h exchange (tag 0 == "h_0 ready", payload 0).
    // buffer 1 needs no init: polls are exact-match on tag, poison/stale never match.
    (void)hipMemsetAsync(hpk, 0, (size_t)NB * 256 * 8, stream);

    k_bias<<<dim3(256), dim3(256), 0, stream>>>(eps_bih, eps_bhh, mask_bih, mask_bhh,
                                                b_ih, b_hh, bias);
    k_xproj<<<dim3(NG / 64, NT / 128, NB), dim3(256), 0, stream>>>(
        seq, eps_ih, mask_ih, w_ih, bias, xproj);
    k_recur<<<dim3(256), dim3(1024), 0, stream>>>(
        eps_hh, mask_hh, w_hh, xproj, hpk, out);
}

// Round 2
// 1878.546 us; speedup vs baseline: 3.0904x; 1.1687x over previous
//
#include <hip/hip_runtime.h>

#define NB 32
#define NT 512
#define NI 512
#define NH 512
#define NG 2048
#define GH (NG*NH)
#define BTH ((size_t)NB*NT*NH)   // 8388608
#define BH  (NB*NH)              // 16384

typedef unsigned int uint;
typedef unsigned long long u64;
typedef _Float16 v2h __attribute__((ext_vector_type(2)));
typedef _Float16 f16x4 __attribute__((ext_vector_type(4)));
typedef _Float16 f16x8 __attribute__((ext_vector_type(8)));
typedef float f32x4 __attribute__((ext_vector_type(4)));
union un8 { f16x4 h[2]; f16x8 v; };

// ---- ws layout (bytes) ----
#define OFF_XPROJ 0
#define SZ_XPROJ  ((size_t)NB*NT*NG*2)            // 64 MB  x_proj bf16 [B][T][G]
#define OFF_BIAS  (OFF_XPROJ + SZ_XPROJ)
#define SZ_BIAS   ((size_t)NB*NG*4)               // 256 KB fp32 bias [B][G]
#define OFF_HP    (OFF_BIAS + SZ_BIAS)
#define SZ_HP     ((size_t)2*NB*256*8)            // 128 KB tagged {f16x2,tag} pairs, dbuf

__device__ __forceinline__ float bf2f(unsigned short u) {
    union { uint i; float f; } v; v.i = ((uint)u) << 16; return v.f;
}
__device__ __forceinline__ unsigned short f2bf(float f) {
    union { uint i; float f; } v; v.f = f;
    uint r = v.i + 0x7FFFu + ((v.i >> 16) & 1u);
    return (unsigned short)(r >> 16);
}
__device__ __forceinline__ uint pkf16(float a, float b) {
    auto p = __builtin_amdgcn_cvt_pkrtz(a, b);   // __fp16 ext_vector(2)
    return __builtin_bit_cast(uint, p);
}
__device__ __forceinline__ float dot2(uint wu, uint hu, float c) {
#if __has_builtin(__builtin_amdgcn_fdot2)
    return __builtin_amdgcn_fdot2(__builtin_bit_cast(v2h, wu),
                                  __builtin_bit_cast(v2h, hu), c, false);
#else
    v2h a = __builtin_bit_cast(v2h, wu), b = __builtin_bit_cast(v2h, hu);
    return c + (float)a[0] * (float)b[0] + (float)a[1] * (float)b[1];
#endif
}
// z = clip(1.2*sigmoid(1.5*(log(eps)-log(1-eps)+m)) - 0.1, 0, 1)
__device__ __forceinline__ float gate_z(float eps, float m) {
    float u = (__logf(eps) - __logf(1.0f - eps) + m) * 1.5f;
    float y = 1.0f / (1.0f + __expf(-u));
    float z = fmaf(y, 1.2f, -0.1f);
    return fminf(fmaxf(z, 0.0f), 1.0f);
}
__device__ __forceinline__ float sigmoidf_(float x) {
    return 1.0f / (1.0f + __expf(-x));
}
__device__ __forceinline__ float tanhf_(float x) {
    return 1.0f - 2.0f / (__expf(2.0f * x) + 1.0f);
}
// LDS swizzle for hsh: 2-way max bank aliasing for 16B reads (free per m136)
__device__ __forceinline__ int hswz(int kg, int r, int u) {
    return (kg << 4) + (((r + (kg >> 1)) & 3) << 2) + u;
}
// k-index XOR swizzle for xproj LDS tiles (rows stride 512 f16 = bank-degenerate)
__device__ __forceinline__ int kswz(int row, int k) {
    return k ^ ((row & 7) << 2);
}

// ---------- bias[b][g] ----------
__global__ __launch_bounds__(256) void k_bias(
    const float* __restrict__ eb1, const float* __restrict__ eb2,
    const float* __restrict__ mb1, const float* __restrict__ mb2,
    const float* __restrict__ b1, const float* __restrict__ b2,
    float* __restrict__ bias) {
    int idx = blockIdx.x * 256 + threadIdx.x;
    int g = idx & (NG - 1);
    bias[idx] = gate_z(eb1[idx], mb1[g]) * b1[g] + gate_z(eb2[idx], mb2[g]) * b2[g];
}

// ---------- x_proj[b][t][g], f16 MFMA ----------
// block: 512 thr (8 waves), owns g-tile 64 x all T. Gated W^T f16 resident in
// LDS (staged once: gate_z evaluated once per weight element). t-chunks of 64.
// wave w: m-off (w&3)*16 (t), n-off (w>>2)*32 (g); M_rep=1, N_rep=2.
// frag k-layout: elem j <-> k = (lane>>4)*4 + (j&3) + 16*(j>>2)  [m156 tr-read]
__global__ __launch_bounds__(512, 2) void k_xproj(
    const float* __restrict__ seq, const float* __restrict__ eps_ih,
    const float* __restrict__ mask_ih, const float* __restrict__ w_ih,
    const float* __restrict__ bias, unsigned short* __restrict__ xproj) {
    __shared__ _Float16 Wl[64][512];   // [g][k swizzled]  64 KB
    __shared__ _Float16 Al[64][512];   // [t][k swizzled]  64 KB
    int g0 = blockIdx.x << 6;
    int b  = blockIdx.y;
    int tid = threadIdx.x;
    int w = tid >> 6, lane = tid & 63;
    int lr = lane & 15, lg = lane >> 4;
    int mo = (w & 3) << 4, no = (w >> 2) << 5;

    // ---- stage gated W (once) ----
    {
        int g = tid >> 3, k0 = (tid & 7) << 6;
        size_t moff = (size_t)(g0 + g) * NI + k0;
        const float4* ep = (const float4*)(eps_ih + (size_t)b * GH + moff);
        const float4* mp = (const float4*)(mask_ih + moff);
        const float4* wp = (const float4*)(w_ih + moff);
#pragma unroll
        for (int q = 0; q < 16; ++q) {
            float4 e = ep[q], m = mp[q], wv = wp[q];
            f16x4 o;
            o[0] = (_Float16)(gate_z(e.x, m.x) * wv.x);
            o[1] = (_Float16)(gate_z(e.y, m.y) * wv.y);
            o[2] = (_Float16)(gate_z(e.z, m.z) * wv.z);
            o[3] = (_Float16)(gate_z(e.w, m.w) * wv.w);
            *(f16x4*)&Wl[g][kswz(g, k0 + (q << 2))] = o;
        }
    }

    float bs0 = bias[b * NG + g0 + no + lr];
    float bs1 = bias[b * NG + g0 + no + 16 + lr];
    int ra = mo + lr, rb0 = no + lr, rb1 = no + 16 + lr;

    for (int tc = 0; tc < NT; tc += 64) {
        // ---- stage A chunk (fp32 seq -> f16) ----
        {
            int r = tid >> 3, k0 = (tid & 7) << 6;
            const float4* sp = (const float4*)(seq + (size_t)(b * NT + tc + r) * NI + k0);
#pragma unroll
            for (int q = 0; q < 16; ++q) {
                float4 v = sp[q];
                f16x4 o;
                o[0] = (_Float16)v.x; o[1] = (_Float16)v.y;
                o[2] = (_Float16)v.z; o[3] = (_Float16)v.w;
                *(f16x4*)&Al[r][kswz(r, k0 + (q << 2))] = o;
            }
        }
        __syncthreads();

        f32x4 acc0 = {0.f, 0.f, 0.f, 0.f}, acc1 = {0.f, 0.f, 0.f, 0.f};
#pragma unroll
        for (int i0 = 0; i0 < NI; i0 += 32) {
            int k0 = i0 + (lg << 2);
            un8 a, b0, b1;
            a.h[0]  = *(const f16x4*)&Al[ra][kswz(ra, k0)];
            a.h[1]  = *(const f16x4*)&Al[ra][kswz(ra, k0 + 16)];
            b0.h[0] = *(const f16x4*)&Wl[rb0][kswz(rb0, k0)];
            b0.h[1] = *(const f16x4*)&Wl[rb0][kswz(rb0, k0 + 16)];
            b1.h[0] = *(const f16x4*)&Wl[rb1][kswz(rb1, k0)];
            b1.h[1] = *(const f16x4*)&Wl[rb1][kswz(rb1, k0 + 16)];
            acc0 = __builtin_amdgcn_mfma_f32_16x16x32_f16(a.v, b0.v, acc0, 0, 0, 0);
            acc1 = __builtin_amdgcn_mfma_f32_16x16x32_f16(a.v, b1.v, acc1, 0, 0, 0);
        }
        // ---- epilogue: +bias, bf16 store. C/D: col=lane&15, row=(lane>>4)*4+reg
#pragma unroll
        for (int r = 0; r < 4; ++r) {
            int t = tc + mo + (lg << 2) + r;
            unsigned short* op = xproj + ((size_t)(b * NT + t) << 11) + g0 + no + lr;
            op[0]  = f2bf(acc0[r] + bs0);
            op[16] = f2bf(acc1[r] + bs1);
        }
        __syncthreads();   // Al WAR guard before next chunk's staging
    }
}

// ---------- Persistent recurrence: weights resident in VGPRs ----------
// 256 blocks x 1024 threads, 1 block/CU. block bb: batch b=bb>>3, slice (bb&7)*64.
// thread: wave wv, lane l; j = slice*64 + wv*4 + (l>>4); kg = l&15 owns 32 k's.
// h exchange: single tagged 8B relaxed agent-scope atomic per h-pair.
// Activations lane-spread: after the butterfly all 16 lanes hold a0..a3; lane
// kg&3 computes gate (kg&3)'s activation branchlessly (tanh = 2*sig(2x)-1) and
// loads its own gate's xproj addend; leader gathers via 4 uniform shfls.
__global__ __launch_bounds__(1024, 4) void k_recur(
    const float* __restrict__ eps, const float* __restrict__ mask,
    const float* __restrict__ w, const unsigned short* __restrict__ xproj,
    u64* __restrict__ hpk, float* __restrict__ out) {
    __shared__ uint hsh[2][256];   // double-buffered packed f16 h pairs (swizzled)
    int bb = blockIdx.x;
    int b = bb >> 3, slice = bb & 7;
    int tid = threadIdx.x;
    int wv = tid >> 6, lane = tid & 63;
    int jj = lane >> 4, kg = lane & 15;
    int j = (slice << 6) + (wv << 2) + jj;
    bool leader = (kg == 0);
    int gsel = kg & 3;

    // ---- one-time: load + gate + f16-pack weights into registers ----
    uint wreg[4][16];
#pragma unroll
    for (int q = 0; q < 4; ++q) {
        size_t off = (size_t)((q << 9) + j) * NH + (kg << 5);
        const float2* ep = (const float2*)(eps + (size_t)b * GH + off);
        const float2* mp = (const float2*)(mask + off);
        const float2* wp = (const float2*)(w + off);
#pragma unroll
        for (int u = 0; u < 16; ++u) {
            float2 e = ep[u], m = mp[u], ww = wp[u];
            wreg[q][u] = pkf16(gate_z(e.x, m.x) * ww.x,
                               gate_z(e.y, m.y) * ww.y);
        }
    }

    // prefetch xproj for t=0: lane kg<4 loads its own gate's addend
    float xp = 0.f;
    if (kg < 4) {
        const unsigned short* xq = xproj + ((size_t)(b * NT) << 11) + j + (gsel << 9);
        xp = bf2f(xq[0]);
    }

    float c = 0.0f;
    for (int t = 0; t < NT; ++t) {
        int par = t & 1;
        // stage remote h pairs: spin on tagged words (relaxed; exact tag match).
        if (tid < 256 && !(t > 0 && (tid >> 5) == slice)) {
            const u64* src = hpk + ((size_t)(par * NB + b) << 8) + tid;
            u64 v;
            do {
                v = __hip_atomic_load(src, __ATOMIC_RELAXED, __HIP_MEMORY_SCOPE_AGENT);
            } while ((uint)(v >> 32) != (uint)t);
            hsh[par][hswz(tid >> 4, (tid >> 2) & 3, tid & 3)] = (uint)v;
        }
        __syncthreads();   // single barrier per step (LDS is double-buffered)

        float a0 = 0.f, a1 = 0.f, a2 = 0.f, a3 = 0.f;
#pragma unroll
        for (int r = 0; r < 4; ++r) {
            uint4 hv = *(const uint4*)&hsh[par][hswz(kg, r, 0)];
            uint hu[4] = {hv.x, hv.y, hv.z, hv.w};
#pragma unroll
            for (int u = 0; u < 4; ++u) {
                a0 = dot2(wreg[0][(r << 2) + u], hu[u], a0);
                a1 = dot2(wreg[1][(r << 2) + u], hu[u], a1);
                a2 = dot2(wreg[2][(r << 2) + u], hu[u], a2);
                a3 = dot2(wreg[3][(r << 2) + u], hu[u], a3);
            }
        }
#pragma unroll
        for (int off = 8; off > 0; off >>= 1) {
            a0 += __shfl_xor(a0, off);
            a1 += __shfl_xor(a1, off);
            a2 += __shfl_xor(a2, off);
            a3 += __shfl_xor(a3, off);
        }
        // lane-spread activations (uniform, no divergence)
        float x = gsel == 0 ? a0 : gsel == 1 ? a1 : gsel == 2 ? a2 : a3;
        x += xp;
        float y = sigmoidf_(gsel == 2 ? 2.0f * x : x);
        float act = gsel == 2 ? fmaf(y, 2.0f, -1.0f) : y;
        int base = lane & 48;
        float ai_ = __shfl(act, base);
        float af_ = __shfl(act, base + 1);
        float ag_ = __shfl(act, base + 2);
        float ao_ = __shfl(act, base + 3);
        if (leader) {
            c = fmaf(af_, c, ai_ * ag_);
            float h = ao_ * tanhf_(c);
            out[((size_t)(b * NT + t) << 9) + j] = h;
            if (t == NT - 1) {
                out[BTH + (size_t)(b << 9) + j] = h;
                out[BTH + BH + (size_t)(b << 9) + j] = c;
            }
            // pack h pair across leader lanes (0<->16, 32<->48; all four active)
            float hpart = __shfl_xor(h, 16);
            if ((lane & 16) == 0) {   // lanes 0 and 32: own pair words
                uint pk = pkf16(h, hpart);           // lo = even j, hi = odd j
                int wd = (slice << 5) + (wv << 1) + (lane >> 5);
                u64 val = ((u64)(uint)(t + 1) << 32) | (u64)pk;
                __hip_atomic_store(hpk + ((size_t)(((t + 1) & 1) * NB + b) << 8) + wd,
                                   val, __ATOMIC_RELAXED, __HIP_MEMORY_SCOPE_AGENT);
                // local shortcut: write own pair straight into next LDS buffer
                hsh[(t + 1) & 1][hswz(wd >> 4, (wd >> 2) & 3, wd & 3)] = pk;
            }
        }
        // prefetch xproj for t+1 (off the critical path; absorbed by next poll)
        if (kg < 4 && t + 1 < NT) {
            const unsigned short* xq =
                xproj + ((size_t)(b * NT + t + 1) << 11) + j + (gsel << 9);
            xp = bf2f(xq[0]);
        }
    }
}

extern "C" void kernel_launch(void* const* d_in, const int* in_sizes, int n_in,
                              void* d_out, int out_size, void* d_ws, size_t ws_size,
                              hipStream_t stream) {
    const float* seq      = (const float*)d_in[0];
    const float* w_ih     = (const float*)d_in[1];
    const float* w_hh     = (const float*)d_in[2];
    const float* b_ih     = (const float*)d_in[3];
    const float* b_hh     = (const float*)d_in[4];
    const float* mask_ih  = (const float*)d_in[5];
    const float* mask_hh  = (const float*)d_in[6];
    const float* mask_bih = (const float*)d_in[7];
    const float* mask_bhh = (const float*)d_in[8];
    const float* eps_ih   = (const float*)d_in[9];
    const float* eps_hh   = (const float*)d_in[10];
    const float* eps_bih  = (const float*)d_in[11];
    const float* eps_bhh  = (const float*)d_in[12];

    char* ws = (char*)d_ws;
    unsigned short* xproj = (unsigned short*)(ws + OFF_XPROJ);
    float* bias  = (float*)(ws + OFF_BIAS);
    u64*   hpk   = (u64*)(ws + OFF_HP);
    float* out   = (float*)d_out;

    // zero buffer 0 of the tagged h exchange (tag 0 == "h_0 ready", payload 0).
    (void)hipMemsetAsync(hpk, 0, (size_t)NB * 256 * 8, stream);

    k_bias<<<dim3(256), dim3(256), 0, stream>>>(eps_bih, eps_bhh, mask_bih, mask_bhh,
                                                b_ih, b_hh, bias);
    k_xproj<<<dim3(NG / 64, NB), dim3(512), 0, stream>>>(
        seq, eps_ih, mask_ih, w_ih, bias, xproj);
    k_recur<<<dim3(256), dim3(1024), 0, stream>>>(
        eps_hh, mask_hh, w_hh, xproj, hpk, out);
}